// Round 4
// baseline (204.668 us; speedup 1.0000x reference)
//
#include <hip/hip_runtime.h>

#define Bb 4
#define Nn 1024
#define Dd 128
#define Hh 64
#define NTILE 16         // 64-row tiles per dim (N/64)

__device__ __forceinline__ float fast_tanh(float x) {
    const float e = __expf(2.0f * x);
    return __fdividef(e - 1.0f, e + 1.0f);
}

// word-index swizzle inside a [rows][32] f32 panel: spread a column across banks
__device__ __forceinline__ int swz32(int row, int cw) {
    return row * 32 + (cw ^ (((row >> 2) & 7) << 2));
}

// ---------------- Kernel A: projection ----------------
// HI2[row][h] = sum_d emb[row][d]*W1[d][h] + b1[h]
// HJ [row][h] = sum_d emb[row][d]*W1[128+d][h]
__global__ __launch_bounds__(512) void proj_kernel(
    const float* __restrict__ emb, const float* __restrict__ W1,
    const float* __restrict__ b1, float* __restrict__ HI2, float* __restrict__ HJ)
{
    __shared__ float se[16][132];
    const int tid = threadIdx.x;
    const int row0 = blockIdx.x * 16;
    {
        const int r = tid >> 5;
        const int c = tid & 31;
        const float4 v = *(const float4*)(emb + (size_t)(row0 + r) * Dd + c * 4);
        *(float4*)&se[r][c * 4] = v;
    }
    __syncthreads();
    const int r  = tid >> 5;
    const int h2 = (tid & 31) * 2;
    float2 acc1 = *(const float2*)(b1 + h2);
    float2 acc2 = make_float2(0.f, 0.f);
    const float* er = se[r];
    #pragma unroll 8
    for (int d = 0; d < Dd; ++d) {
        const float ev = er[d];
        const float2 wa = *(const float2*)(W1 + (size_t)d * Hh + h2);
        const float2 wb = *(const float2*)(W1 + (size_t)(d + Dd) * Hh + h2);
        acc1.x = fmaf(ev, wa.x, acc1.x); acc1.y = fmaf(ev, wa.y, acc1.y);
        acc2.x = fmaf(ev, wb.x, acc2.x); acc2.y = fmaf(ev, wb.y, acc2.y);
    }
    *(float2*)(HI2 + (size_t)(row0 + r) * Hh + h2) = acc1;
    *(float2*)(HJ  + (size_t)(row0 + r) * Hh + h2) = acc2;
}

// ---------------- Kernel B: pair scoring, FULL grid ----------------
// grid = Bb*NTILE*NTILE = 1024 blocks; block 256 threads (16x16), 4x4 micro.
// Each block owns one 64x64 output tile (ti,tj) and computes BOTH directions:
// out[i][j] = -0.5*(tanh(s_ij+b2) + tanh(s_ji+b2)); single coalesced write.
// Two h-phases of 32 keep LDS at 32KB -> exactly 4 blocks/CU, 1024 = 4*256.
__global__ __launch_bounds__(256, 2) void score_kernel(
    const float* __restrict__ HI2, const float* __restrict__ HJ,
    const float* __restrict__ W2, const float* __restrict__ b2p,
    float* __restrict__ out)
{
    __shared__ float sAi[64 * 32];  // HI2 rows of i-range (h-half)
    __shared__ float sBi[64 * 32];  // HJ  rows of i-range
    __shared__ float sAj[64 * 32];  // HI2 rows of j-range
    __shared__ float sBj[64 * 32];  // HJ  rows of j-range
    __shared__ float sW[Hh];

    const int tid = threadIdx.x;
    const int blk = blockIdx.x;
    const int b  = blk >> 8;          // / 256
    const int p  = blk & 255;
    const int ti = p >> 4;
    const int tj = p & 15;
    const int ri0 = ti * 64, rj0 = tj * 64;

    const float* HIb = HI2 + (size_t)b * Nn * Hh;
    const float* HJb = HJ  + (size_t)b * Nn * Hh;

    if (tid < Hh) sW[tid] = W2[tid];

    const int tx = tid & 15;   // j direction
    const int ty = tid >> 4;   // i direction

    float s_ij[4][4];
    float s_ji[4][4];
    #pragma unroll
    for (int r = 0; r < 4; ++r)
        #pragma unroll
        for (int c = 0; c < 4; ++c) { s_ij[r][c] = 0.f; s_ji[r][c] = 0.f; }

    for (int ph = 0; ph < 2; ++ph) {
        if (ph) __syncthreads();   // previous compute must finish before overwrite
        const int h0 = ph * 32;
        // stage 4 panels (each 64 rows x 32 f32 = 512 float4), swizzled
        for (int l = tid; l < 2048; l += 256) {
            const int which = l >> 9;
            const int rem   = l & 511;
            const int row   = rem >> 3;
            const int cw    = (rem & 7) * 4;
            const float* src;
            float* dst;
            if (which == 0)      { src = HIb + (size_t)(ri0 + row) * Hh; dst = sAi; }
            else if (which == 1) { src = HJb + (size_t)(ri0 + row) * Hh; dst = sBi; }
            else if (which == 2) { src = HIb + (size_t)(rj0 + row) * Hh; dst = sAj; }
            else                 { src = HJb + (size_t)(rj0 + row) * Hh; dst = sBj; }
            const float4 v = *(const float4*)(src + h0 + cw);
            *(float4*)&dst[swz32(row, cw)] = v;
        }
        __syncthreads();

        #pragma unroll
        for (int hc = 0; hc < 8; ++hc) {
            const int cw = hc * 4;
            const float4 w = *(const float4*)(sW + h0 + cw);
            float4 ai[4], bi[4], aj[4], bj[4];
            #pragma unroll
            for (int r = 0; r < 4; ++r) {
                ai[r] = *(const float4*)&sAi[swz32(ty * 4 + r, cw)];
                bi[r] = *(const float4*)&sBi[swz32(ty * 4 + r, cw)];
            }
            #pragma unroll
            for (int c = 0; c < 4; ++c) {
                aj[c] = *(const float4*)&sAj[swz32(tx * 4 + c, cw)];
                bj[c] = *(const float4*)&sBj[swz32(tx * 4 + c, cw)];
            }
            #pragma unroll
            for (int r = 0; r < 4; ++r) {
                #pragma unroll
                for (int c = 0; c < 4; ++c) {
                    float t;
                    t = fmaxf(ai[r].x + bj[c].x, 0.f); s_ij[r][c] = fmaf(t, w.x, s_ij[r][c]);
                    t = fmaxf(ai[r].y + bj[c].y, 0.f); s_ij[r][c] = fmaf(t, w.y, s_ij[r][c]);
                    t = fmaxf(ai[r].z + bj[c].z, 0.f); s_ij[r][c] = fmaf(t, w.z, s_ij[r][c]);
                    t = fmaxf(ai[r].w + bj[c].w, 0.f); s_ij[r][c] = fmaf(t, w.w, s_ij[r][c]);
                    t = fmaxf(aj[c].x + bi[r].x, 0.f); s_ji[r][c] = fmaf(t, w.x, s_ji[r][c]);
                    t = fmaxf(aj[c].y + bi[r].y, 0.f); s_ji[r][c] = fmaf(t, w.y, s_ji[r][c]);
                    t = fmaxf(aj[c].z + bi[r].z, 0.f); s_ji[r][c] = fmaf(t, w.z, s_ji[r][c]);
                    t = fmaxf(aj[c].w + bi[r].w, 0.f); s_ji[r][c] = fmaf(t, w.w, s_ji[r][c]);
                }
            }
        }
    }

    const float bb = b2p[0];
    float* outb = out + (size_t)b * Nn * Nn;
    const int i0 = ri0 + ty * 4;
    const int j0 = rj0 + tx * 4;
    // single coalesced write of this block's 64x64 tile
    #pragma unroll
    for (int r = 0; r < 4; ++r) {
        float4 v;
        v.x = -0.5f * (fast_tanh(s_ij[r][0] + bb) + fast_tanh(s_ji[r][0] + bb));
        v.y = -0.5f * (fast_tanh(s_ij[r][1] + bb) + fast_tanh(s_ji[r][1] + bb));
        v.z = -0.5f * (fast_tanh(s_ij[r][2] + bb) + fast_tanh(s_ji[r][2] + bb));
        v.w = -0.5f * (fast_tanh(s_ij[r][3] + bb) + fast_tanh(s_ji[r][3] + bb));
        *(float4*)(outb + (size_t)(i0 + r) * Nn + j0) = v;
    }
}

extern "C" void kernel_launch(void* const* d_in, const int* in_sizes, int n_in,
                              void* d_out, int out_size, void* d_ws, size_t ws_size,
                              hipStream_t stream) {
    const float* emb = (const float*)d_in[0];
    const float* W1  = (const float*)d_in[1];
    const float* b1  = (const float*)d_in[2];
    const float* W2  = (const float*)d_in[3];
    const float* b2  = (const float*)d_in[4];
    float* out = (float*)d_out;
    float* HI2 = (float*)d_ws;                       // 4096*64 f32 = 1 MB
    float* HJ  = HI2 + (size_t)Bb * Nn * Hh;         // 1 MB

    proj_kernel<<<(Bb * Nn) / 16, 512, 0, stream>>>(emb, W1, b1, HI2, HJ);
    score_kernel<<<Bb * NTILE * NTILE, 256, 0, stream>>>(HI2, HJ, W2, b2, out);
}

// Round 5
// 118.916 us; speedup vs baseline: 1.7211x; 1.7211x over previous
//
#include <hip/hip_runtime.h>

#define Bb 4
#define Nn 1024
#define Dd 128
#define Hh 64
#define NTILE 16         // 64-row tiles per dim (N/64)

__device__ __forceinline__ float fast_tanh(float x) {
    const float e = __expf(2.0f * x);
    return __fdividef(e - 1.0f, e + 1.0f);
}

// word-index swizzle inside a [64][64] f32 panel: rotate 16B slots by row group
__device__ __forceinline__ int swzA(int row, int cw) {
    return row * Hh + (cw ^ (((row >> 2) & 7) << 2));
}

// ---------------- Kernel A: projection ----------------
// HI2[row][h] = sum_d emb[row][d]*W1[d][h] + b1[h]
// HJ [row][h] = sum_d emb[row][d]*W1[128+d][h]
__global__ __launch_bounds__(512) void proj_kernel(
    const float* __restrict__ emb, const float* __restrict__ W1,
    const float* __restrict__ b1, float* __restrict__ HI2, float* __restrict__ HJ)
{
    __shared__ float se[16][132];
    const int tid = threadIdx.x;
    const int row0 = blockIdx.x * 16;
    {
        const int r = tid >> 5;
        const int c = tid & 31;
        const float4 v = *(const float4*)(emb + (size_t)(row0 + r) * Dd + c * 4);
        *(float4*)&se[r][c * 4] = v;
    }
    __syncthreads();
    const int r  = tid >> 5;
    const int h2 = (tid & 31) * 2;
    float2 acc1 = *(const float2*)(b1 + h2);
    float2 acc2 = make_float2(0.f, 0.f);
    const float* er = se[r];
    #pragma unroll 8
    for (int d = 0; d < Dd; ++d) {
        const float ev = er[d];
        const float2 wa = *(const float2*)(W1 + (size_t)d * Hh + h2);
        const float2 wb = *(const float2*)(W1 + (size_t)(d + Dd) * Hh + h2);
        acc1.x = fmaf(ev, wa.x, acc1.x); acc1.y = fmaf(ev, wa.y, acc1.y);
        acc2.x = fmaf(ev, wb.x, acc2.x); acc2.y = fmaf(ev, wb.y, acc2.y);
    }
    *(float2*)(HI2 + (size_t)(row0 + r) * Hh + h2) = acc1;
    *(float2*)(HJ  + (size_t)(row0 + r) * Hh + h2) = acc2;
}

// ---------------- Kernel B: one-directional raw scores ----------------
// grid = Bb*256 blocks; block 256 thr (16x16), 4x4 micro-tile, 64x64 tile.
// S[b,i,j] = sum_h relu(HI2[i,h]+HJ[j,h]) * W2[h]   (no tanh, no symmetrize)
// Register budget: 16 acc + 8 live float4 loads ≈ 70 VGPR -> no spills.
__global__ __launch_bounds__(256) void score_kernel(
    const float* __restrict__ HI2, const float* __restrict__ HJ,
    const float* __restrict__ W2, float* __restrict__ S)
{
    __shared__ float sA[64 * Hh];   // HI2 rows of i-range, swizzled
    __shared__ float sB[64 * Hh];   // HJ  rows of j-range, swizzled
    __shared__ float sW[Hh];

    const int tid = threadIdx.x;
    const int blk = blockIdx.x;
    const int b  = blk >> 8;
    const int p  = blk & 255;
    const int ti = p >> 4;
    const int tj = p & 15;
    const int ri0 = ti * 64, rj0 = tj * 64;

    const float* HIb = HI2 + ((size_t)b * Nn + ri0) * Hh;
    const float* HJb = HJ  + ((size_t)b * Nn + rj0) * Hh;

    if (tid < Hh) sW[tid] = W2[tid];

    // stage 2 panels (64 rows x 64 f32 each = 1024 float4 per panel)
    #pragma unroll
    for (int k = 0; k < 8; ++k) {
        const int l = tid + k * 256;
        const int panel = l >> 10;          // uniform per k
        const int rem   = l & 1023;
        const int row   = rem >> 4;
        const int cw    = (rem & 15) * 4;
        const float4 v = *(const float4*)((panel ? HJb : HIb) + row * Hh + cw);
        float* dst = panel ? sB : sA;
        *(float4*)&dst[swzA(row, cw)] = v;
    }
    __syncthreads();

    const int tx = tid & 15;   // j direction
    const int ty = tid >> 4;   // i direction
    const int ar0 = ty * 4, br0 = tx * 4;

    float acc[4][4];
    #pragma unroll
    for (int r = 0; r < 4; ++r)
        #pragma unroll
        for (int c = 0; c < 4; ++c) acc[r][c] = 0.f;

    #pragma unroll 2
    for (int hc = 0; hc < 16; ++hc) {
        const int cw = hc * 4;
        const float4 w = *(const float4*)(sW + cw);
        float4 a[4], bj[4];
        #pragma unroll
        for (int r = 0; r < 4; ++r) a[r]  = *(const float4*)&sA[swzA(ar0 + r, cw)];
        #pragma unroll
        for (int c = 0; c < 4; ++c) bj[c] = *(const float4*)&sB[swzA(br0 + c, cw)];
        #pragma unroll
        for (int r = 0; r < 4; ++r) {
            #pragma unroll
            for (int c = 0; c < 4; ++c) {
                float t;
                t = fmaxf(a[r].x + bj[c].x, 0.f); acc[r][c] = fmaf(t, w.x, acc[r][c]);
                t = fmaxf(a[r].y + bj[c].y, 0.f); acc[r][c] = fmaf(t, w.y, acc[r][c]);
                t = fmaxf(a[r].z + bj[c].z, 0.f); acc[r][c] = fmaf(t, w.z, acc[r][c]);
                t = fmaxf(a[r].w + bj[c].w, 0.f); acc[r][c] = fmaf(t, w.w, acc[r][c]);
            }
        }
    }

    float* Sb = S + (size_t)b * Nn * Nn;
    const int i0 = ri0 + ar0;
    const int j0 = rj0 + br0;
    #pragma unroll
    for (int r = 0; r < 4; ++r) {
        float4 v = make_float4(acc[r][0], acc[r][1], acc[r][2], acc[r][3]);
        *(float4*)(Sb + (size_t)(i0 + r) * Nn + j0) = v;
    }
}

// ---------------- Kernel C: symmetrize + tanh ----------------
// out[b,i,j] = -0.5*(tanh(S[b,i,j]+b2) + tanh(S[b,j,i]+b2))
// Transposed tile staged via padded LDS; all global accesses coalesced.
__global__ __launch_bounds__(256) void sym_kernel(
    const float* __restrict__ S, const float* __restrict__ b2p,
    float* __restrict__ out)
{
    __shared__ float bT[64][68];    // row stride 272 B (16B-aligned, odd bank tilt)
    const int tid = threadIdx.x;
    const int blk = blockIdx.x;
    const int b  = blk >> 8;
    const int p  = blk & 255;
    const int ti = p >> 4;
    const int tj = p & 15;
    const int i0 = ti * 64, j0 = tj * 64;
    const float* Sb = S + (size_t)b * Nn * Nn;

    // stage tile S[j0..j0+63][i0..i0+63] (the transpose source), coalesced
    #pragma unroll
    for (int k = 0; k < 4; ++k) {
        const int l = tid + k * 256;
        const int jj = l >> 4;
        const int c4 = (l & 15) * 4;
        const float4 v = *(const float4*)(Sb + (size_t)(j0 + jj) * Nn + i0 + c4);
        *(float4*)&bT[jj][c4] = v;
    }
    __syncthreads();

    const float bb = b2p[0];
    const int tx = tid & 15;
    const int ty = tid >> 4;
    float* outb = out + (size_t)b * Nn * Nn;

    #pragma unroll
    for (int r = 0; r < 4; ++r) {
        const int i = ty * 4 + r;
        const float4 a = *(const float4*)(Sb + (size_t)(i0 + i) * Nn + j0 + tx * 4);
        float4 v;
        v.x = -0.5f * (fast_tanh(a.x + bb) + fast_tanh(bT[tx * 4 + 0][i] + bb));
        v.y = -0.5f * (fast_tanh(a.y + bb) + fast_tanh(bT[tx * 4 + 1][i] + bb));
        v.z = -0.5f * (fast_tanh(a.z + bb) + fast_tanh(bT[tx * 4 + 2][i] + bb));
        v.w = -0.5f * (fast_tanh(a.w + bb) + fast_tanh(bT[tx * 4 + 3][i] + bb));
        *(float4*)(outb + (size_t)(i0 + i) * Nn + j0 + tx * 4) = v;
    }
}

extern "C" void kernel_launch(void* const* d_in, const int* in_sizes, int n_in,
                              void* d_out, int out_size, void* d_ws, size_t ws_size,
                              hipStream_t stream) {
    const float* emb = (const float*)d_in[0];
    const float* W1  = (const float*)d_in[1];
    const float* b1  = (const float*)d_in[2];
    const float* W2  = (const float*)d_in[3];
    const float* b2  = (const float*)d_in[4];
    float* out = (float*)d_out;
    float* HI2 = (float*)d_ws;                        // 1 MB
    float* HJ  = HI2 + (size_t)Bb * Nn * Hh;          // 1 MB
    float* S   = HJ  + (size_t)Bb * Nn * Hh;          // 16.8 MB raw scores

    proj_kernel<<<(Bb * Nn) / 16, 512, 0, stream>>>(emb, W1, b1, HI2, HJ);
    score_kernel<<<Bb * 256, 256, 0, stream>>>(HI2, HJ, W2, S);
    sym_kernel<<<Bb * 256, 256, 0, stream>>>(S, b2, out);
}